// Round 7
// baseline (590.735 us; speedup 1.0000x reference)
//
#include <hip/hip_runtime.h>

typedef unsigned short u16;
typedef unsigned char u8;
typedef unsigned int u32;
typedef __bf16 bf16x8 __attribute__((ext_vector_type(8)));
typedef float f32x4 __attribute__((ext_vector_type(4)));

constexpr int BATCH = 8;
constexpr int C = 256;
constexpr int H = 64;
constexpr int W = 64;
constexpr int HW = H * W;          // 4096
constexpr int HH = 62, WW = 62;    // valid patch grid
constexpr int NQ = HH * WW;        // 3844
constexpr int SEG = 8;             // y-steps per reduce block
constexpr int NBLK_RED = 536;      // sum over diagonals of ceil(len/SEG)

// ws layout (bytes)
constexpr size_t OFF_RNORM = 0;            // 2*8*4096*4 = 262144
constexpr size_t OFF_RESV = 262144;        // 8*3844*4 = 123008 (pad 123136)
constexpr size_t OFF_RESI = 385280;
constexpr size_t OFF_SLOT0 = 508416;
// per-slot layout. pval8 (reduce value partials, 3844*512*4 = 7,872,512 B)
// OVERLAYS the operand region [0, 8 MB) — operands are dead after pgemm.
// pidx8 (u8 bb indices, 3844*512 = 1,968,128 B) after Q.
constexpr size_t SP_H1 = 0;                // 4096*256*2 = 2,097,152
constexpr size_t SP_L1 = 2097152;
constexpr size_t SP_H2 = 4194304;
constexpr size_t SP_L2 = 6291456;
constexpr size_t SP_P = 8388608;           // QT: 4096 planes * 16KB = 67,108,864
constexpr size_t SP_PIDX8 = 75497472;      // 1,968,128 B (pad to 2 MB)
constexpr size_t SLOT_BYTES = 77594624;

// async global->LDS, 16B per lane (LDS dest: wave-uniform base + lane*16)
typedef const __attribute__((address_space(1))) unsigned int* gas_ptr;
typedef __attribute__((address_space(3))) unsigned int* las_ptr;
__device__ __forceinline__ void gl16(const void* g, void* l) {
  __builtin_amdgcn_global_load_lds((gas_ptr)g, (las_ptr)l, 16, 0, 0);
}

// prefix over diagonal lengths: len(m) = 62 - |m-61|
__device__ __forceinline__ int pre_of(int ki) {
  if (ki <= 62) return ki * (ki + 1) / 2;
  int r = 123 - ki;                       // 60..1
  return 1953 + 1891 - r * (r + 1) / 2;
}

// ---------------------------------------------------------------------------
// Kernel 1: per-position reciprocal channel-L2 norm. rnorm[tensor][b][pos]
// ---------------------------------------------------------------------------
__global__ __launch_bounds__(256) void norm_kernel(const float* __restrict__ f1,
                                                   const float* __restrict__ f2,
                                                   float* __restrict__ rnorm) {
  int by = blockIdx.x;           // b*H + y
  int tensor = blockIdx.y;
  const float* f = tensor ? f2 : f1;
  int b = by >> 6, y = by & 63;
  int x = threadIdx.x & 63;
  int cq = threadIdx.x >> 6;
  const float* base = f + ((size_t)b * C) * HW + y * W + x;
  float s = 0.f;
  for (int c = cq; c < C; c += 4) {
    float v = base[(size_t)c * HW];
    s = fmaf(v, v, s);
  }
  __shared__ float sm[4][64];
  sm[cq][x] = s;
  __syncthreads();
  if (threadIdx.x < 64) {
    float t = sm[0][x] + sm[1][x] + sm[2][x] + sm[3][x];
    float nrm = fmaxf(sqrtf(t), 1e-12f);
    rnorm[((size_t)tensor * BATCH + b) * HW + y * W + x] = 1.0f / nrm;
  }
}

// ---------------------------------------------------------------------------
// Kernel 2: normalize + hi/lo bf16 split into SEPARATE u16 planes [pos][c].
// ---------------------------------------------------------------------------
__global__ __launch_bounds__(256) void convert_kernel(const float* __restrict__ f1,
                                                      const float* __restrict__ f2,
                                                      const float* __restrict__ rnorm,
                                                      int bi,
                                                      u16* __restrict__ hi1, u16* __restrict__ lo1,
                                                      u16* __restrict__ hi2, u16* __restrict__ lo2) {
  int chunk = blockIdx.x;        // 0..127, 32 positions each
  int tensor = blockIdx.y;
  int pos0 = chunk * 32;
  const float* f = (tensor ? f2 : f1) + (size_t)bi * C * HW;
  const float* rn = rnorm + ((size_t)tensor * BATCH + bi) * HW + pos0;
  u16* dh = (tensor ? hi2 : hi1) + (size_t)pos0 * C;
  u16* dl = (tensor ? lo2 : lo1) + (size_t)pos0 * C;

  __shared__ u32 sm[32][257];
  int t = threadIdx.x;
  int px = t & 31, cg = t >> 5;  // cg 0..7
  float r = rn[px];
  for (int kk = 0; kk < 32; ++kk) {
    int c = (cg << 5) + kk;
    float v = f[(size_t)c * HW + pos0 + px] * r;
    __bf16 h = (__bf16)v;        // RNE
    float hf = (float)h;
    __bf16 lo = (__bf16)(v - hf);
    sm[px][c] = ((u32)__builtin_bit_cast(u16, h) << 16) | (u32)__builtin_bit_cast(u16, lo);
  }
  __syncthreads();
  int px2 = t >> 3, seg = t & 7;
  int c0 = seg * 32;
  for (int g8 = 0; g8 < 4; ++g8) {
    u32 hw0, hw1, hw2, hw3, lw0, lw1, lw2, lw3;
    u32 a, b2;
    a = sm[px2][c0 + g8 * 8 + 0]; b2 = sm[px2][c0 + g8 * 8 + 1];
    hw0 = (a >> 16) | (b2 & 0xFFFF0000u); lw0 = (a & 0xFFFFu) | (b2 << 16);
    a = sm[px2][c0 + g8 * 8 + 2]; b2 = sm[px2][c0 + g8 * 8 + 3];
    hw1 = (a >> 16) | (b2 & 0xFFFF0000u); lw1 = (a & 0xFFFFu) | (b2 << 16);
    a = sm[px2][c0 + g8 * 8 + 4]; b2 = sm[px2][c0 + g8 * 8 + 5];
    hw2 = (a >> 16) | (b2 & 0xFFFF0000u); lw2 = (a & 0xFFFFu) | (b2 << 16);
    a = sm[px2][c0 + g8 * 8 + 6]; b2 = sm[px2][c0 + g8 * 8 + 7];
    hw3 = (a >> 16) | (b2 & 0xFFFF0000u); lw3 = (a & 0xFFFFu) | (b2 << 16);
    size_t off = (size_t)px2 * C + c0 + g8 * 8;
    uint4 hv; hv.x = hw0; hv.y = hw1; hv.z = hw2; hv.w = hw3;
    uint4 lv; lv.x = lw0; lv.y = lw1; lv.z = lw2; lv.w = lw3;
    *(uint4*)(dh + off) = hv;
    *(uint4*)(dl + off) = lv;
  }
}

// ---------------------------------------------------------------------------
// Kernel 3: split-bf16 3-product MFMA GEMM + Q-epilogue.
// Computes P-tile 128x128 (= 2x2 complete 64x64 planes), then in-block
// computes Q[ix][jx] = P[ix,jx]+P[ix+1,jx+1]+P[ix+2,jx+2] (within-plane
// diagonal 3-sum) and stores Q TRANSPOSED [jx(bx)][ix(ax)], plane-major.
// ---------------------------------------------------------------------------
__global__ __launch_bounds__(256, 2) void pgemm_kernel(const u16* __restrict__ hi1,
                                                       const u16* __restrict__ lo1,
                                                       const u16* __restrict__ hi2,
                                                       const u16* __restrict__ lo2,
                                                       float* __restrict__ P) {
  int bid = blockIdx.x;
  int swz = (bid & 7) * 128 + (bid >> 3);   // bijective XCD swizzle (1024 blocks)
  int p0 = (swz >> 5) << 7, q0 = (swz & 31) << 7;

  __shared__ __align__(16) char smem[65536];
  char* sAh = smem;
  char* sAl = smem + 16384;
  char* sBh = smem + 32768;
  char* sBl = smem + 49152;

  int t = threadIdx.x;
  int l = t & 63, w = t >> 6, wm = w >> 1, wn = w & 1;
  int lr = l & 15, lh = l >> 4;
  int wv = w;

  const u16* src0 = hi1 + (size_t)p0 * 256;
  const u16* src1 = lo1 + (size_t)p0 * 256;
  const u16* src2 = hi2 + (size_t)q0 * 256;
  const u16* src3 = lo2 + (size_t)q0 * 256;

  f32x4 acc[4][4];
#pragma unroll
  for (int mf = 0; mf < 4; ++mf)
#pragma unroll
    for (int nf = 0; nf < 4; ++nf)
      acc[mf][nf] = (f32x4){0.f, 0.f, 0.f, 0.f};

  for (int kt = 0; kt < 4; ++kt) {
    if (kt) __syncthreads();
#pragma unroll
    for (int qq = 0; qq < 4; ++qq) {
      int q = wv * 4 + qq;
      int row = q * 8 + (l >> 3);
      int cc = l & 7;
      size_t goff = (size_t)row * 256 + kt * 64 + ((cc ^ (row & 7)) << 3);
      gl16(src0 + goff, sAh + q * 1024);
      gl16(src1 + goff, sAl + q * 1024);
      gl16(src2 + goff, sBh + q * 1024);
      gl16(src3 + goff, sBl + q * 1024);
    }
    __syncthreads();
#pragma unroll
    for (int ks = 0; ks < 2; ++ks) {
      bf16x8 ah[4], al[4];
#pragma unroll
      for (int mf = 0; mf < 4; ++mf) {
        int row = wm * 64 + mf * 16 + lr;
        int off = row * 128 + ((((ks * 4 + lh) << 4)) ^ ((row & 7) << 4));
        ah[mf] = *(const bf16x8*)(sAh + off);
        al[mf] = *(const bf16x8*)(sAl + off);
      }
#pragma unroll
      for (int nf = 0; nf < 4; ++nf) {
        int row = wn * 64 + nf * 16 + lr;
        int off = row * 128 + ((((ks * 4 + lh) << 4)) ^ ((row & 7) << 4));
        bf16x8 bh = *(const bf16x8*)(sBh + off);
        bf16x8 bl = *(const bf16x8*)(sBl + off);
#pragma unroll
        for (int mf = 0; mf < 4; ++mf) {
          acc[mf][nf] = __builtin_amdgcn_mfma_f32_16x16x32_bf16(ah[mf], bh, acc[mf][nf], 0, 0, 0);
          acc[mf][nf] = __builtin_amdgcn_mfma_f32_16x16x32_bf16(al[mf], bh, acc[mf][nf], 0, 0, 0);
          acc[mf][nf] = __builtin_amdgcn_mfma_f32_16x16x32_bf16(ah[mf], bl, acc[mf][nf], 0, 0, 0);
        }
      }
    }
  }

  // ---- Q epilogue: 2 passes x 2 planes. Buffers [64][68] f32 (16B rows).
  __syncthreads();                 // all MFMA LDS reads done
  float* sq = (float*)smem;
#pragma unroll
  for (int pass = 0; pass < 2; ++pass) {
    if (pass) __syncthreads();     // prev pass reads done before overwrite
    if (wn == pass) {
      // stage my 64x64 quadrant; C/D layout: col=lane&15, row=(lane>>4)*4+reg
      float* buf = sq + wm * 4352;
#pragma unroll
      for (int mf = 0; mf < 4; ++mf)
#pragma unroll
        for (int nf = 0; nf < 4; ++nf)
#pragma unroll
          for (int j = 0; j < 4; ++j)
            buf[(mf * 16 + lh * 4 + j) * 68 + nf * 16 + lr] = acc[mf][nf][j];
      buf[l * 68 + 64] = 0.f;      // init pads (edge reads stay finite)
      buf[l * 68 + 65] = 0.f;
    }
    __syncthreads();
    // all 256 threads: sel = buffer, r = Q row (ax), half = jx half
    int sel = t >> 7, r = (t >> 1) & 63, half = t & 1;
    const float* S = sq + sel * 4352;
    int r1 = r + 1 > 63 ? 63 : r + 1;
    int r2 = r + 2 > 63 ? 63 : r + 2;
    const float* S0 = S + r * 68;
    const float* S1 = S + r1 * 68;
    const float* S2 = S + r2 * 68;
    int planeIdx = (((p0 >> 6) + sel) << 6) + (q0 >> 6) + pass;
    float* Qg = P + (((size_t)planeIdx) << 12) + r;   // QT[jx][ax]: + jx*64
#pragma unroll
    for (int gi = 0; gi < 8; ++gi) {
      int g = half * 8 + gi;
      f32x4 a = *(const f32x4*)(S0 + g * 4);
      f32x4 b0 = *(const f32x4*)(S1 + g * 4);
      f32x4 c0 = *(const f32x4*)(S2 + g * 4);
      float b4 = S1[g * 4 + 4];
      float c4 = S2[g * 4 + 4];
      float c5 = S2[g * 4 + 5];
      Qg[(size_t)(g * 4 + 0) * 64] = a[0] + b0[1] + c0[2];
      Qg[(size_t)(g * 4 + 1) * 64] = a[1] + b0[2] + c0[3];
      Qg[(size_t)(g * 4 + 2) * 64] = a[2] + b0[3] + c4;
      Qg[(size_t)(g * 4 + 3) * 64] = a[3] + b4 + c5;
    }
  }
}

// ---------------------------------------------------------------------------
// Kernel 4: barrier-free register-rolling diagonal reduce. Block = (diag k,
// SEG segment) x slot; thread (w,l) = (bx-group, ax). Per plane: 8 coalesced
// scalar loads Dg[s] = QT[w*8+s][l]; roll A,B + 3-deep prefetch P0/P1/P2;
// exact per-lane argmax -> pval8 (f32) + pidx8 (u8). No LDS, no barriers.
// ---------------------------------------------------------------------------
__global__ __launch_bounds__(512) void reduce_kernel(char* __restrict__ slot0,
                                                     size_t slotBytes) {
  int slot = blockIdx.y;
  char* sb = slot0 + (size_t)slot * slotBytes;
  const float* QT = (const float*)(sb + SP_P);
  float* pval8 = (float*)sb;               // overlay on operand region
  u8* pidx8 = (u8*)(sb + SP_PIDX8);

  // map blockIdx.x -> (ki, segment)
  int bid = blockIdx.x;
  int ki = 0;
  for (ki = 0; ki < 123; ++ki) {
    int d = ki - 61; if (d < 0) d = -d;
    int ns = (62 - d + SEG - 1) / SEG;
    if (bid < ns) break;
    bid -= ns;
  }
  int k = ki - 61;
  int ystart = k < 0 ? -k : 0;
  int yend = k > 0 ? 61 - k : 61;
  int y0 = ystart + bid * SEG;
  int y1 = y0 + SEG; if (y1 > yend + 1) y1 = yend + 1;
  int sid0 = pre_of(ki) + (y0 - ystart);
  int pmax = yend + 2;               // last valid plane on this diagonal

  int t = threadIdx.x;
  int w = t >> 6, l = t & 63;

  float A[8], B[8], P0[8], P1[8], P2[8];

  auto ld = [&](int p, float* D) {
    const float* gp = QT + (((size_t)((p << 6) + (p + k))) << 12) + (w << 9) + l;
#pragma unroll
    for (int s = 0; s < 8; ++s) D[s] = gp[s << 6];
  };

  auto candstep = [&](int y, const float* D0, const float* D1, const float* D2) {
    float best = __uint_as_float(0xFF800000u);
    int bbb = 0;
#pragma unroll
    for (int s = 0; s < 8; ++s) {
      float c = D0[s] + D1[s] + D2[s];
      bool valid = (w * 8 + s) <= 61;
      if (valid && c > best) { best = c; bbb = s; }  // ascending s: first max
    }
    size_t o = (size_t)(sid0 + (y - y0)) * 512 + (w << 6) + l;
    pval8[o] = best;
    pidx8[o] = (u8)bbb;
  };

  ld(y0, A);
  ld(y0 + 1, B);
  ld(y0 + 2, P0);
  ld(y0 + 3 > pmax ? pmax : y0 + 3, P1);
  ld(y0 + 4 > pmax ? pmax : y0 + 4, P2);

  int y = y0;
  while (true) {
    candstep(y, A, B, P0);
#pragma unroll
    for (int s = 0; s < 8; ++s) { A[s] = B[s]; B[s] = P0[s]; }
    if (++y >= y1) break;
    ld(y + 4 > pmax ? pmax : y + 4, P0);
    candstep(y, A, B, P1);
#pragma unroll
    for (int s = 0; s < 8; ++s) { A[s] = B[s]; B[s] = P1[s]; }
    if (++y >= y1) break;
    ld(y + 4 > pmax ? pmax : y + 4, P1);
    candstep(y, A, B, P2);
#pragma unroll
    for (int s = 0; s < 8; ++s) { A[s] = B[s]; B[s] = P2[s]; }
    if (++y >= y1) break;
    ld(y + 4 > pmax ? pmax : y + 4, P2);
  }
}

// ---------------------------------------------------------------------------
// Kernel 5: combine partials over (jy, w) with exact compares; decode bb via
// one pidx8 read. Strict > with ascending (jy, w) preserves first-occurrence.
// ---------------------------------------------------------------------------
__global__ __launch_bounds__(256) void combine_kernel(const char* __restrict__ slot0,
                                                      size_t slotBytes, int b0,
                                                      float* __restrict__ resv,
                                                      int* __restrict__ residx) {
  int q = blockIdx.x * 256 + threadIdx.x;
  if (q >= NQ) return;
  int slot = blockIdx.y;
  int b = b0 + slot;
  const char* sb = slot0 + (size_t)slot * slotBytes;
  const float* pval8 = (const float*)sb;
  const u8* pidx8 = (const u8*)(sb + SP_PIDX8);
  int y = q / 62, ax = q - y * 62;
  float best = __uint_as_float(0xFF800000u);
  int bjy = 0, bw = 0;
  for (int jy = 0; jy < 62; ++jy) {
    int ki = 61 + jy - y;
    int sid = pre_of(ki) + (y < jy ? y : jy);
    const float* p = pval8 + (size_t)sid * 512 + ax;
#pragma unroll
    for (int ww = 0; ww < 8; ++ww) {
      float v = p[ww << 6];
      if (v > best) { best = v; bjy = jy; bw = ww; }
    }
  }
  int kib = 61 + bjy - y;
  int sidb = pre_of(kib) + (y < bjy ? y : bjy);
  int bb = pidx8[(size_t)sidb * 512 + (bw << 6) + ax];
  resv[(size_t)b * NQ + q] = best;
  residx[(size_t)b * NQ + q] = bjy * 62 + bw * 8 + bb;
}

// ---------------------------------------------------------------------------
// Kernel 6: assemble flow (B,64,64,2), offset (B,9,64,64,2), sim (B,1,64,64).
// ---------------------------------------------------------------------------
__global__ __launch_bounds__(256) void assemble_kernel(const float* __restrict__ res_val,
                                                       const int* __restrict__ res_idx,
                                                       float* __restrict__ out) {
  int gid = blockIdx.x * 256 + threadIdx.x;
  if (gid >= BATCH * HW) return;
  int b = gid >> 12;
  int y = (gid >> 6) & 63;
  int x = gid & 63;

  float* out_flow = out;
  float* out_off = out + (size_t)BATCH * HW * 2;
  float* out_sim = out + (size_t)BATCH * HW * 2 + (size_t)BATCH * 9 * HW * 2;

  auto flow_at = [&](int yy, int xx, float* fx, float* fy) {
    if (yy >= 0 && yy < HH && xx >= 0 && xx < WW) {
      int idx = res_idx[(size_t)b * NQ + yy * WW + xx];
      *fx = (float)(idx % WW - xx);
      *fy = (float)(idx / WW - yy);
    } else {
      *fx = 0.f;
      *fy = 0.f;
    }
  };

  float fx, fy;
  flow_at(y, x, &fx, &fy);
  size_t fo = ((size_t)b * HW + y * W + x) * 2;
  out_flow[fo + 0] = fx;
  out_flow[fo + 1] = fy;

#pragma unroll
  for (int sft = 0; sft < 9; ++sft) {
    int i = sft / 3, j = sft % 3;
    float ox, oy;
    flow_at(y - i, x - j, &ox, &oy);
    size_t o = (((size_t)b * 9 + sft) * HW + y * W + x) * 2;
    out_off[o + 0] = ox;
    out_off[o + 1] = oy;
  }

  float sim = 0.f;
  if (y >= 1 && y <= HH && x >= 1 && x <= WW) {
    float mv = res_val[(size_t)b * NQ + (y - 1) * WW + (x - 1)];
    sim = mv * (1.0f / ((3.0f + 1e-5f) * 3.0f));  // patch norms are exactly 3
  }
  out_sim[(size_t)b * HW + y * W + x] = sim;
}

// ---------------------------------------------------------------------------
extern "C" void kernel_launch(void* const* d_in, const int* in_sizes, int n_in,
                              void* d_out, int out_size, void* d_ws, size_t ws_size,
                              hipStream_t stream) {
  const float* f1 = (const float*)d_in[0];
  const float* f2 = (const float*)d_in[1];
  float* out = (float*)d_out;
  char* ws = (char*)d_ws;

  float* rnorm = (float*)(ws + OFF_RNORM);
  float* resv = (float*)(ws + OFF_RESV);
  int* residx = (int*)(ws + OFF_RESI);
  char* slot0 = ws + OFF_SLOT0;

  // adaptive image-group size from available workspace (deterministic)
  int nslots = 1;
  if (ws_size > OFF_SLOT0 + SLOT_BYTES) {
    size_t n = (ws_size - OFF_SLOT0) / SLOT_BYTES;
    nslots = n >= 8 ? 8 : (int)n;
    if (nslots < 1) nslots = 1;
  }

  norm_kernel<<<dim3(BATCH * H, 2), 256, 0, stream>>>(f1, f2, rnorm);

  for (int b0 = 0; b0 < BATCH; b0 += nslots) {
    int g = BATCH - b0 < nslots ? BATCH - b0 : nslots;
    for (int i = 0; i < g; ++i) {
      char* slot = slot0 + (size_t)i * SLOT_BYTES;
      convert_kernel<<<dim3(128, 2), 256, 0, stream>>>(
          f1, f2, rnorm, b0 + i,
          (u16*)(slot + SP_H1), (u16*)(slot + SP_L1),
          (u16*)(slot + SP_H2), (u16*)(slot + SP_L2));
      pgemm_kernel<<<1024, 256, 0, stream>>>(
          (const u16*)(slot + SP_H1), (const u16*)(slot + SP_L1),
          (const u16*)(slot + SP_H2), (const u16*)(slot + SP_L2),
          (float*)(slot + SP_P));
    }
    reduce_kernel<<<dim3(NBLK_RED, g), 512, 0, stream>>>(slot0, SLOT_BYTES);
    combine_kernel<<<dim3(16, g), 256, 0, stream>>>(slot0, SLOT_BYTES, b0,
                                                    resv, residx);
  }

  int total = BATCH * HW;
  assemble_kernel<<<(total + 255) / 256, 256, 0, stream>>>(resv, residx, out);
}

// Round 9
// 551.235 us; speedup vs baseline: 1.0717x; 1.0717x over previous
//
#include <hip/hip_runtime.h>

typedef unsigned short u16;
typedef unsigned char u8;
typedef unsigned int u32;
typedef __bf16 bf16x8 __attribute__((ext_vector_type(8)));
typedef float f32x4 __attribute__((ext_vector_type(4)));

constexpr int BATCH = 8;
constexpr int C = 256;
constexpr int H = 64;
constexpr int W = 64;
constexpr int HW = H * W;          // 4096
constexpr int HH = 62, WW = 62;    // valid patch grid
constexpr int NQ = HH * WW;        // 3844
constexpr int SEG = 8;             // y-steps per reduce block
constexpr int NBLK_RED = 536;      // sum over diagonals of ceil(len/SEG)

// ws layout (bytes)
constexpr size_t OFF_RNORM = 0;            // 2*8*4096*4 = 262144
constexpr size_t OFF_RESV = 262144;        // 8*3844*4 = 123008 (pad 123136)
constexpr size_t OFF_RESI = 385280;
constexpr size_t OFF_SLOT0 = 508416;
// per-slot layout. pval8 (3844*512*4 = 7,872,512 B) OVERLAYS the operand
// region [0, 8MB) — operands are dead after pgemm. pidx8 after Q.
constexpr size_t SP_H1 = 0;                // 4096*256*2 = 2,097,152
constexpr size_t SP_L1 = 2097152;
constexpr size_t SP_H2 = 4194304;
constexpr size_t SP_L2 = 6291456;
constexpr size_t SP_P = 8388608;           // Q: 4096 planes * 16KB
constexpr size_t SP_PIDX8 = 75497472;      // 1,968,128 B (pad to 2MB)
constexpr size_t SLOT_BYTES = 77594624;

// async global->LDS, 16B per lane (LDS dest: wave-uniform base + lane*16)
typedef const __attribute__((address_space(1))) unsigned int* gas_ptr;
typedef __attribute__((address_space(3))) unsigned int* las_ptr;
__device__ __forceinline__ void gl16(const void* g, void* l) {
  __builtin_amdgcn_global_load_lds((gas_ptr)g, (las_ptr)l, 16, 0, 0);
}

// prefix over diagonal lengths: len(m) = 62 - |m-61|
__device__ __forceinline__ int pre_of(int ki) {
  if (ki <= 62) return ki * (ki + 1) / 2;
  int r = 123 - ki;                       // 60..1
  return 1953 + 1891 - r * (r + 1) / 2;
}

// ---------------------------------------------------------------------------
// Kernel 1: per-position reciprocal channel-L2 norm. rnorm[tensor][b][pos]
// ---------------------------------------------------------------------------
__global__ __launch_bounds__(256) void norm_kernel(const float* __restrict__ f1,
                                                   const float* __restrict__ f2,
                                                   float* __restrict__ rnorm) {
  int by = blockIdx.x;           // b*H + y
  int tensor = blockIdx.y;
  const float* f = tensor ? f2 : f1;
  int b = by >> 6, y = by & 63;
  int x = threadIdx.x & 63;
  int cq = threadIdx.x >> 6;
  const float* base = f + ((size_t)b * C) * HW + y * W + x;
  float s = 0.f;
  for (int c = cq; c < C; c += 4) {
    float v = base[(size_t)c * HW];
    s = fmaf(v, v, s);
  }
  __shared__ float sm[4][64];
  sm[cq][x] = s;
  __syncthreads();
  if (threadIdx.x < 64) {
    float t = sm[0][x] + sm[1][x] + sm[2][x] + sm[3][x];
    float nrm = fmaxf(sqrtf(t), 1e-12f);
    rnorm[((size_t)tensor * BATCH + b) * HW + y * W + x] = 1.0f / nrm;
  }
}

// ---------------------------------------------------------------------------
// Kernel 2: normalize + hi/lo bf16 split into SEPARATE u16 planes [pos][c].
// Merged over slots: grid (128 chunks, 2 tensors, g slots).
// ---------------------------------------------------------------------------
__global__ __launch_bounds__(256) void convert_kernel(const float* __restrict__ f1,
                                                      const float* __restrict__ f2,
                                                      const float* __restrict__ rnorm,
                                                      int b0, char* __restrict__ slot0) {
  int chunk = blockIdx.x;        // 0..127, 32 positions each
  int tensor = blockIdx.y;
  int sloti = blockIdx.z;
  int bi = b0 + sloti;
  char* slot = slot0 + (size_t)sloti * SLOT_BYTES;
  int pos0 = chunk * 32;
  const float* f = (tensor ? f2 : f1) + (size_t)bi * C * HW;
  const float* rn = rnorm + ((size_t)tensor * BATCH + bi) * HW + pos0;
  u16* dh = (u16*)(slot + (tensor ? SP_H2 : SP_H1)) + (size_t)pos0 * C;
  u16* dl = (u16*)(slot + (tensor ? SP_L2 : SP_L1)) + (size_t)pos0 * C;

  __shared__ u32 sm[32][257];
  int t = threadIdx.x;
  int px = t & 31, cg = t >> 5;  // cg 0..7
  float r = rn[px];
  for (int kk = 0; kk < 32; ++kk) {
    int c = (cg << 5) + kk;
    float v = f[(size_t)c * HW + pos0 + px] * r;
    __bf16 h = (__bf16)v;        // RNE
    float hf = (float)h;
    __bf16 lo = (__bf16)(v - hf);
    sm[px][c] = ((u32)__builtin_bit_cast(u16, h) << 16) | (u32)__builtin_bit_cast(u16, lo);
  }
  __syncthreads();
  int px2 = t >> 3, seg = t & 7;
  int c0 = seg * 32;
  for (int g8 = 0; g8 < 4; ++g8) {
    u32 hw0, hw1, hw2, hw3, lw0, lw1, lw2, lw3;
    u32 a, b2;
    a = sm[px2][c0 + g8 * 8 + 0]; b2 = sm[px2][c0 + g8 * 8 + 1];
    hw0 = (a >> 16) | (b2 & 0xFFFF0000u); lw0 = (a & 0xFFFFu) | (b2 << 16);
    a = sm[px2][c0 + g8 * 8 + 2]; b2 = sm[px2][c0 + g8 * 8 + 3];
    hw1 = (a >> 16) | (b2 & 0xFFFF0000u); lw1 = (a & 0xFFFFu) | (b2 << 16);
    a = sm[px2][c0 + g8 * 8 + 4]; b2 = sm[px2][c0 + g8 * 8 + 5];
    hw2 = (a >> 16) | (b2 & 0xFFFF0000u); lw2 = (a & 0xFFFFu) | (b2 << 16);
    a = sm[px2][c0 + g8 * 8 + 6]; b2 = sm[px2][c0 + g8 * 8 + 7];
    hw3 = (a >> 16) | (b2 & 0xFFFF0000u); lw3 = (a & 0xFFFFu) | (b2 << 16);
    size_t off = (size_t)px2 * C + c0 + g8 * 8;
    uint4 hv; hv.x = hw0; hv.y = hw1; hv.z = hw2; hv.w = hw3;
    uint4 lv; lv.x = lw0; lv.y = lw1; lv.z = lw2; lv.w = lw3;
    *(uint4*)(dh + off) = hv;
    *(uint4*)(dl + off) = lv;
  }
}

// ---------------------------------------------------------------------------
// Kernel 3: split-bf16 3-product MFMA GEMM + Q-epilogue. MFMA core identical
// to R7 (verified). Epilogue stores Q in layout [plane][jx>>3][ax][jx&7]
// (coalesced 32B/lane stores; enables vectorized reduce loads).
// Grid (1024 tiles, g slots).
// ---------------------------------------------------------------------------
__global__ __launch_bounds__(256, 2) void pgemm_kernel(char* __restrict__ slot0) {
  char* slot = slot0 + (size_t)blockIdx.y * SLOT_BYTES;
  const u16* hi1 = (const u16*)(slot + SP_H1);
  const u16* lo1 = (const u16*)(slot + SP_L1);
  const u16* hi2 = (const u16*)(slot + SP_H2);
  const u16* lo2 = (const u16*)(slot + SP_L2);
  float* P = (float*)(slot + SP_P);

  int bid = blockIdx.x;
  int swz = (bid & 7) * 128 + (bid >> 3);   // bijective XCD swizzle (1024 blocks)
  int p0 = (swz >> 5) << 7, q0 = (swz & 31) << 7;

  __shared__ __align__(16) char smem[65536];
  char* sAh = smem;
  char* sAl = smem + 16384;
  char* sBh = smem + 32768;
  char* sBl = smem + 49152;

  int t = threadIdx.x;
  int l = t & 63, w = t >> 6, wm = w >> 1, wn = w & 1;
  int lr = l & 15, lh = l >> 4;
  int wv = w;

  const u16* src0 = hi1 + (size_t)p0 * 256;
  const u16* src1 = lo1 + (size_t)p0 * 256;
  const u16* src2 = hi2 + (size_t)q0 * 256;
  const u16* src3 = lo2 + (size_t)q0 * 256;

  f32x4 acc[4][4];
#pragma unroll
  for (int mf = 0; mf < 4; ++mf)
#pragma unroll
    for (int nf = 0; nf < 4; ++nf)
      acc[mf][nf] = (f32x4){0.f, 0.f, 0.f, 0.f};

  for (int kt = 0; kt < 4; ++kt) {
    if (kt) __syncthreads();
#pragma unroll
    for (int qq = 0; qq < 4; ++qq) {
      int q = wv * 4 + qq;
      int row = q * 8 + (l >> 3);
      int cc = l & 7;
      size_t goff = (size_t)row * 256 + kt * 64 + ((cc ^ (row & 7)) << 3);
      gl16(src0 + goff, sAh + q * 1024);
      gl16(src1 + goff, sAl + q * 1024);
      gl16(src2 + goff, sBh + q * 1024);
      gl16(src3 + goff, sBl + q * 1024);
    }
    __syncthreads();
#pragma unroll
    for (int ks = 0; ks < 2; ++ks) {
      bf16x8 ah[4], al[4];
#pragma unroll
      for (int mf = 0; mf < 4; ++mf) {
        int row = wm * 64 + mf * 16 + lr;
        int off = row * 128 + ((((ks * 4 + lh) << 4)) ^ ((row & 7) << 4));
        ah[mf] = *(const bf16x8*)(sAh + off);
        al[mf] = *(const bf16x8*)(sAl + off);
      }
#pragma unroll
      for (int nf = 0; nf < 4; ++nf) {
        int row = wn * 64 + nf * 16 + lr;
        int off = row * 128 + ((((ks * 4 + lh) << 4)) ^ ((row & 7) << 4));
        bf16x8 bh = *(const bf16x8*)(sBh + off);
        bf16x8 bl = *(const bf16x8*)(sBl + off);
#pragma unroll
        for (int mf = 0; mf < 4; ++mf) {
          acc[mf][nf] = __builtin_amdgcn_mfma_f32_16x16x32_bf16(ah[mf], bh, acc[mf][nf], 0, 0, 0);
          acc[mf][nf] = __builtin_amdgcn_mfma_f32_16x16x32_bf16(al[mf], bh, acc[mf][nf], 0, 0, 0);
          acc[mf][nf] = __builtin_amdgcn_mfma_f32_16x16x32_bf16(ah[mf], bl, acc[mf][nf], 0, 0, 0);
        }
      }
    }
  }

  // ---- Q epilogue: 2 passes x 2 planes. Staged P quadrant [64][68] in LDS.
  __syncthreads();                 // all MFMA LDS reads done
  float* sq = (float*)smem;
#pragma unroll
  for (int pass = 0; pass < 2; ++pass) {
    if (pass) __syncthreads();     // prev pass reads done before overwrite
    if (wn == pass) {
      float* buf = sq + wm * 4352;
#pragma unroll
      for (int mf = 0; mf < 4; ++mf)
#pragma unroll
        for (int nf = 0; nf < 4; ++nf)
#pragma unroll
          for (int j = 0; j < 4; ++j)
            buf[(mf * 16 + lh * 4 + j) * 68 + nf * 16 + lr] = acc[mf][nf][j];
      *(f32x4*)(buf + l * 68 + 64) = (f32x4){0.f, 0.f, 0.f, 0.f};  // pads
    }
    __syncthreads();
    int tid2 = t & 127, sel = t >> 7;
    int ax = tid2 & 63, halfj = tid2 >> 6;
    const float* S = sq + sel * 4352;
    int rr1 = ax + 1 > 63 ? 63 : ax + 1;
    int rr2 = ax + 2 > 63 ? 63 : ax + 2;
    const float* S0 = S + ax * 68;
    const float* S1 = S + rr1 * 68;
    const float* S2 = S + rr2 * 68;
    int planeIdx = (((p0 >> 6) + sel) << 6) + (q0 >> 6) + pass;
    float* Qg = P + (((size_t)planeIdx) << 12) + ax * 8;
#pragma unroll
    for (int gi = 0; gi < 4; ++gi) {
      int g = halfj * 4 + gi;
      int c0 = g * 8;
      float r0[12], r1a[12], r2a[12];
#pragma unroll
      for (int u = 0; u < 3; ++u) {
        *(f32x4*)(r0 + u * 4) = *(const f32x4*)(S0 + c0 + u * 4);
        *(f32x4*)(r1a + u * 4) = *(const f32x4*)(S1 + c0 + u * 4);
        *(f32x4*)(r2a + u * 4) = *(const f32x4*)(S2 + c0 + u * 4);
      }
      f32x4 qv0, qv1;
#pragma unroll
      for (int e = 0; e < 4; ++e) qv0[e] = r0[e] + r1a[e + 1] + r2a[e + 2];
#pragma unroll
      for (int e = 0; e < 4; ++e) qv1[e] = r0[e + 4] + r1a[e + 5] + r2a[e + 6];
      *(f32x4*)(Qg + (size_t)g * 512) = qv0;
      *(f32x4*)(Qg + (size_t)g * 512 + 4) = qv1;
    }
  }
}

// ---------------------------------------------------------------------------
// Kernel 4: barrier-free register-rolling diagonal reduce (R7 logic, now
// with 2x f32x4 plane loads from the [g][ax][e] layout; wave reads 2KB
// contiguous per plane). No LDS, no barriers.
// ---------------------------------------------------------------------------
__global__ __launch_bounds__(512) void reduce_kernel(char* __restrict__ slot0,
                                                     size_t slotBytes) {
  int slot = blockIdx.y;
  char* sb = slot0 + (size_t)slot * slotBytes;
  const float* QT = (const float*)(sb + SP_P);
  float* pval8 = (float*)sb;               // overlay on operand region
  u8* pidx8 = (u8*)(sb + SP_PIDX8);

  // map blockIdx.x -> (ki, segment)
  int bid = blockIdx.x;
  int ki = 0;
  for (ki = 0; ki < 123; ++ki) {
    int d = ki - 61; if (d < 0) d = -d;
    int ns = (62 - d + SEG - 1) / SEG;
    if (bid < ns) break;
    bid -= ns;
  }
  int k = ki - 61;
  int ystart = k < 0 ? -k : 0;
  int yend = k > 0 ? 61 - k : 61;
  int y0 = ystart + bid * SEG;
  int y1 = y0 + SEG; if (y1 > yend + 1) y1 = yend + 1;
  int sid0 = pre_of(ki) + (y0 - ystart);
  int pmax = yend + 2;               // last valid plane on this diagonal

  int t = threadIdx.x;
  int w = t >> 6, l = t & 63;

  float A[8], B[8], P0[8], P1[8], P2[8];

  auto ld = [&](int p, float* D) {
    const float* gp = QT + (((size_t)((p << 6) + (p + k))) << 12) + (w << 9) + (l << 3);
    *(f32x4*)(D) = *(const f32x4*)(gp);
    *(f32x4*)(D + 4) = *(const f32x4*)(gp + 4);
  };

  auto candstep = [&](int y, const float* D0, const float* D1, const float* D2) {
    float best = __uint_as_float(0xFF800000u);
    int bbb = 0;
#pragma unroll
    for (int s = 0; s < 8; ++s) {
      float c = D0[s] + D1[s] + D2[s];
      bool valid = (w * 8 + s) <= 61;
      if (valid && c > best) { best = c; bbb = s; }  // ascending s: first max
    }
    size_t o = (size_t)(sid0 + (y - y0)) * 512 + (w << 6) + l;
    pval8[o] = best;
    pidx8[o] = (u8)bbb;
  };

  ld(y0, A);
  ld(y0 + 1, B);
  ld(y0 + 2, P0);
  ld(y0 + 3 > pmax ? pmax : y0 + 3, P1);
  ld(y0 + 4 > pmax ? pmax : y0 + 4, P2);

  int y = y0;
  while (true) {
    candstep(y, A, B, P0);
#pragma unroll
    for (int s = 0; s < 8; ++s) { A[s] = B[s]; B[s] = P0[s]; }
    if (++y >= y1) break;
    ld(y + 4 > pmax ? pmax : y + 4, P0);
    candstep(y, A, B, P1);
#pragma unroll
    for (int s = 0; s < 8; ++s) { A[s] = B[s]; B[s] = P1[s]; }
    if (++y >= y1) break;
    ld(y + 4 > pmax ? pmax : y + 4, P1);
    candstep(y, A, B, P2);
#pragma unroll
    for (int s = 0; s < 8; ++s) { A[s] = B[s]; B[s] = P2[s]; }
    if (++y >= y1) break;
    ld(y + 4 > pmax ? pmax : y + 4, P2);
  }
}

// ---------------------------------------------------------------------------
// Kernel 5: combine partials over (jy, w) with exact compares; decode bb via
// one pidx8 read. Strict > with ascending (jy, w) preserves first-occurrence.
// ---------------------------------------------------------------------------
__global__ __launch_bounds__(256) void combine_kernel(const char* __restrict__ slot0,
                                                      size_t slotBytes, int b0,
                                                      float* __restrict__ resv,
                                                      int* __restrict__ residx) {
  int q = blockIdx.x * 256 + threadIdx.x;
  if (q >= NQ) return;
  int slot = blockIdx.y;
  int b = b0 + slot;
  const char* sb = slot0 + (size_t)slot * slotBytes;
  const float* pval8 = (const float*)sb;
  const u8* pidx8 = (const u8*)(sb + SP_PIDX8);
  int y = q / 62, ax = q - y * 62;
  float best = __uint_as_float(0xFF800000u);
  int bjy = 0, bw = 0;
  for (int jy = 0; jy < 62; ++jy) {
    int ki = 61 + jy - y;
    int sid = pre_of(ki) + (y < jy ? y : jy);
    const float* p = pval8 + (size_t)sid * 512 + ax;
#pragma unroll
    for (int ww = 0; ww < 8; ++ww) {
      float v = p[ww << 6];
      if (v > best) { best = v; bjy = jy; bw = ww; }
    }
  }
  int kib = 61 + bjy - y;
  int sidb = pre_of(kib) + (y < bjy ? y : bjy);
  int bb = pidx8[(size_t)sidb * 512 + (bw << 6) + ax];
  resv[(size_t)b * NQ + q] = best;
  residx[(size_t)b * NQ + q] = bjy * 62 + bw * 8 + bb;
}

// ---------------------------------------------------------------------------
// Kernel 6: assemble flow (B,64,64,2), offset (B,9,64,64,2), sim (B,1,64,64).
// ---------------------------------------------------------------------------
__global__ __launch_bounds__(256) void assemble_kernel(const float* __restrict__ res_val,
                                                       const int* __restrict__ res_idx,
                                                       float* __restrict__ out) {
  int gid = blockIdx.x * 256 + threadIdx.x;
  if (gid >= BATCH * HW) return;
  int b = gid >> 12;
  int y = (gid >> 6) & 63;
  int x = gid & 63;

  float* out_flow = out;
  float* out_off = out + (size_t)BATCH * HW * 2;
  float* out_sim = out + (size_t)BATCH * HW * 2 + (size_t)BATCH * 9 * HW * 2;

  auto flow_at = [&](int yy, int xx, float* fx, float* fy) {
    if (yy >= 0 && yy < HH && xx >= 0 && xx < WW) {
      int idx = res_idx[(size_t)b * NQ + yy * WW + xx];
      *fx = (float)(idx % WW - xx);
      *fy = (float)(idx / WW - yy);
    } else {
      *fx = 0.f;
      *fy = 0.f;
    }
  };

  float fx, fy;
  flow_at(y, x, &fx, &fy);
  size_t fo = ((size_t)b * HW + y * W + x) * 2;
  out_flow[fo + 0] = fx;
  out_flow[fo + 1] = fy;

#pragma unroll
  for (int sft = 0; sft < 9; ++sft) {
    int i = sft / 3, j = sft % 3;
    float ox, oy;
    flow_at(y - i, x - j, &ox, &oy);
    size_t o = (((size_t)b * 9 + sft) * HW + y * W + x) * 2;
    out_off[o + 0] = ox;
    out_off[o + 1] = oy;
  }

  float sim = 0.f;
  if (y >= 1 && y <= HH && x >= 1 && x <= WW) {
    float mv = res_val[(size_t)b * NQ + (y - 1) * WW + (x - 1)];
    sim = mv * (1.0f / ((3.0f + 1e-5f) * 3.0f));  // patch norms are exactly 3
  }
  out_sim[(size_t)b * HW + y * W + x] = sim;
}

// ---------------------------------------------------------------------------
extern "C" void kernel_launch(void* const* d_in, const int* in_sizes, int n_in,
                              void* d_out, int out_size, void* d_ws, size_t ws_size,
                              hipStream_t stream) {
  const float* f1 = (const float*)d_in[0];
  const float* f2 = (const float*)d_in[1];
  float* out = (float*)d_out;
  char* ws = (char*)d_ws;

  float* rnorm = (float*)(ws + OFF_RNORM);
  float* resv = (float*)(ws + OFF_RESV);
  int* residx = (int*)(ws + OFF_RESI);
  char* slot0 = ws + OFF_SLOT0;

  // adaptive image-group size from available workspace (deterministic)
  int nslots = 1;
  if (ws_size > OFF_SLOT0 + SLOT_BYTES) {
    size_t n = (ws_size - OFF_SLOT0) / SLOT_BYTES;
    nslots = n >= 8 ? 8 : (int)n;
    if (nslots < 1) nslots = 1;
  }

  norm_kernel<<<dim3(BATCH * H, 2), 256, 0, stream>>>(f1, f2, rnorm);

  for (int b0 = 0; b0 < BATCH; b0 += nslots) {
    int g = BATCH - b0 < nslots ? BATCH - b0 : nslots;
    convert_kernel<<<dim3(128, 2, g), 256, 0, stream>>>(f1, f2, rnorm, b0, slot0);
    pgemm_kernel<<<dim3(1024, g), 256, 0, stream>>>(slot0);
    reduce_kernel<<<dim3(NBLK_RED, g), 512, 0, stream>>>(slot0, SLOT_BYTES);
    combine_kernel<<<dim3(16, g), 256, 0, stream>>>(slot0, SLOT_BYTES, b0,
                                                    resv, residx);
  }

  int total = BATCH * HW;
  assemble_kernel<<<(total + 255) / 256, 256, 0, stream>>>(resv, residx, out);
}

// Round 10
// 540.749 us; speedup vs baseline: 1.0924x; 1.0194x over previous
//
#include <hip/hip_runtime.h>

typedef unsigned short u16;
typedef unsigned char u8;
typedef unsigned int u32;
typedef __bf16 bf16x8 __attribute__((ext_vector_type(8)));
typedef float f32x4 __attribute__((ext_vector_type(4)));

constexpr int BATCH = 8;
constexpr int C = 256;
constexpr int H = 64;
constexpr int W = 64;
constexpr int HW = H * W;          // 4096
constexpr int HH = 62, WW = 62;    // valid patch grid
constexpr int NQ = HH * WW;        // 3844
constexpr int SEG = 8;             // y-steps per reduce block
constexpr int NBLK_RED = 536;      // sum over diagonals of ceil(len/SEG)

// ws layout (bytes)
constexpr size_t OFF_RNORM = 0;            // 2*8*4096*4 = 262144
constexpr size_t OFF_RESV = 262144;        // 8*3844*4 = 123008 (pad 123136)
constexpr size_t OFF_RESI = 385280;
constexpr size_t OFF_SLOT0 = 508416;
// per-slot layout. pval8 (3844*512*4 = 7,872,512 B) OVERLAYS the operand
// region [0, 8MB) — operands are dead after pgemm. pidx8 after Q.
constexpr size_t SP_H1 = 0;                // 4096*256*2 = 2,097,152
constexpr size_t SP_L1 = 2097152;
constexpr size_t SP_H2 = 4194304;
constexpr size_t SP_L2 = 6291456;
constexpr size_t SP_P = 8388608;           // Q: 4096 planes * 16KB
constexpr size_t SP_PIDX8 = 75497472;      // 1,968,128 B (pad to 2MB)
constexpr size_t SLOT_BYTES = 77594624;

// async global->LDS, 16B per lane (LDS dest: wave-uniform base + lane*16)
typedef const __attribute__((address_space(1))) unsigned int* gas_ptr;
typedef __attribute__((address_space(3))) unsigned int* las_ptr;
__device__ __forceinline__ void gl16(const void* g, void* l) {
  __builtin_amdgcn_global_load_lds((gas_ptr)g, (las_ptr)l, 16, 0, 0);
}

// prefix over diagonal lengths: len(m) = 62 - |m-61|
__device__ __forceinline__ int pre_of(int ki) {
  if (ki <= 62) return ki * (ki + 1) / 2;
  int r = 123 - ki;                       // 60..1
  return 1953 + 1891 - r * (r + 1) / 2;
}

// ---------------------------------------------------------------------------
// Kernel 1: per-position reciprocal channel-L2 norm. rnorm[tensor][b][pos]
// ---------------------------------------------------------------------------
__global__ __launch_bounds__(256) void norm_kernel(const float* __restrict__ f1,
                                                   const float* __restrict__ f2,
                                                   float* __restrict__ rnorm) {
  int by = blockIdx.x;           // b*H + y
  int tensor = blockIdx.y;
  const float* f = tensor ? f2 : f1;
  int b = by >> 6, y = by & 63;
  int x = threadIdx.x & 63;
  int cq = threadIdx.x >> 6;
  const float* base = f + ((size_t)b * C) * HW + y * W + x;
  float s = 0.f;
  for (int c = cq; c < C; c += 4) {
    float v = base[(size_t)c * HW];
    s = fmaf(v, v, s);
  }
  __shared__ float sm[4][64];
  sm[cq][x] = s;
  __syncthreads();
  if (threadIdx.x < 64) {
    float t = sm[0][x] + sm[1][x] + sm[2][x] + sm[3][x];
    float nrm = fmaxf(sqrtf(t), 1e-12f);
    rnorm[((size_t)tensor * BATCH + b) * HW + y * W + x] = 1.0f / nrm;
  }
}

// ---------------------------------------------------------------------------
// Kernel 2: normalize + hi/lo bf16 split into SEPARATE u16 planes [pos][c].
// Merged over slots: grid (128 chunks, 2 tensors, g slots).
// ---------------------------------------------------------------------------
__global__ __launch_bounds__(256) void convert_kernel(const float* __restrict__ f1,
                                                      const float* __restrict__ f2,
                                                      const float* __restrict__ rnorm,
                                                      int b0, char* __restrict__ slot0) {
  int chunk = blockIdx.x;        // 0..127, 32 positions each
  int tensor = blockIdx.y;
  int sloti = blockIdx.z;
  int bi = b0 + sloti;
  char* slot = slot0 + (size_t)sloti * SLOT_BYTES;
  int pos0 = chunk * 32;
  const float* f = (tensor ? f2 : f1) + (size_t)bi * C * HW;
  const float* rn = rnorm + ((size_t)tensor * BATCH + bi) * HW + pos0;
  u16* dh = (u16*)(slot + (tensor ? SP_H2 : SP_H1)) + (size_t)pos0 * C;
  u16* dl = (u16*)(slot + (tensor ? SP_L2 : SP_L1)) + (size_t)pos0 * C;

  __shared__ u32 sm[32][257];
  int t = threadIdx.x;
  int px = t & 31, cg = t >> 5;  // cg 0..7
  float r = rn[px];
  for (int kk = 0; kk < 32; ++kk) {
    int c = (cg << 5) + kk;
    float v = f[(size_t)c * HW + pos0 + px] * r;
    __bf16 h = (__bf16)v;        // RNE
    float hf = (float)h;
    __bf16 lo = (__bf16)(v - hf);
    sm[px][c] = ((u32)__builtin_bit_cast(u16, h) << 16) | (u32)__builtin_bit_cast(u16, lo);
  }
  __syncthreads();
  int px2 = t >> 3, seg = t & 7;
  int c0 = seg * 32;
  for (int g8 = 0; g8 < 4; ++g8) {
    u32 hw0, hw1, hw2, hw3, lw0, lw1, lw2, lw3;
    u32 a, b2;
    a = sm[px2][c0 + g8 * 8 + 0]; b2 = sm[px2][c0 + g8 * 8 + 1];
    hw0 = (a >> 16) | (b2 & 0xFFFF0000u); lw0 = (a & 0xFFFFu) | (b2 << 16);
    a = sm[px2][c0 + g8 * 8 + 2]; b2 = sm[px2][c0 + g8 * 8 + 3];
    hw1 = (a >> 16) | (b2 & 0xFFFF0000u); lw1 = (a & 0xFFFFu) | (b2 << 16);
    a = sm[px2][c0 + g8 * 8 + 4]; b2 = sm[px2][c0 + g8 * 8 + 5];
    hw2 = (a >> 16) | (b2 & 0xFFFF0000u); lw2 = (a & 0xFFFFu) | (b2 << 16);
    a = sm[px2][c0 + g8 * 8 + 6]; b2 = sm[px2][c0 + g8 * 8 + 7];
    hw3 = (a >> 16) | (b2 & 0xFFFF0000u); lw3 = (a & 0xFFFFu) | (b2 << 16);
    size_t off = (size_t)px2 * C + c0 + g8 * 8;
    uint4 hv; hv.x = hw0; hv.y = hw1; hv.z = hw2; hv.w = hw3;
    uint4 lv; lv.x = lw0; lv.y = lw1; lv.z = lw2; lv.w = lw3;
    *(uint4*)(dh + off) = hv;
    *(uint4*)(dl + off) = lv;
  }
}

// ---------------------------------------------------------------------------
// Kernel 3: split-bf16 3-product MFMA GEMM + Q-epilogue.
// BK=32, double-buffered LDS (2 x 4 planes x 8KB = 64KB), 2-phase pipeline:
// STAGE(buf^1, kt+1) issued BEFORE MFMA(buf); one __syncthreads per K-tile.
// K accumulation order identical to R9 (bit-exact canary).
// Q epilogue stores layout [g(8)][h(2)][ax(64)][e(4)] — each wave store
// instruction covers a contiguous 1KB run (no partial-line RMW).
// ---------------------------------------------------------------------------
__global__ __launch_bounds__(256, 2) void pgemm_kernel(char* __restrict__ slot0) {
  char* slot = slot0 + (size_t)blockIdx.y * SLOT_BYTES;
  const u16* hi1 = (const u16*)(slot + SP_H1);
  const u16* lo1 = (const u16*)(slot + SP_L1);
  const u16* hi2 = (const u16*)(slot + SP_H2);
  const u16* lo2 = (const u16*)(slot + SP_L2);
  float* P = (float*)(slot + SP_P);

  int bid = blockIdx.x;
  int swz = (bid & 7) * 128 + (bid >> 3);   // bijective XCD swizzle (1024 blocks)
  int p0 = (swz >> 5) << 7, q0 = (swz & 31) << 7;

  __shared__ __align__(16) char smem[65536];   // 2 buffers x 32KB

  int t = threadIdx.x;
  int l = t & 63, w = t >> 6, wm = w >> 1, wn = w & 1;
  int lr = l & 15, lh = l >> 4;

  const u16* srcs[4] = {hi1 + (size_t)p0 * 256, lo1 + (size_t)p0 * 256,
                        hi2 + (size_t)q0 * 256, lo2 + (size_t)q0 * 256};

  f32x4 acc[4][4];
#pragma unroll
  for (int mf = 0; mf < 4; ++mf)
#pragma unroll
    for (int nf = 0; nf < 4; ++nf)
      acc[mf][nf] = (f32x4){0.f, 0.f, 0.f, 0.f};

  // stage K-tile kt (32 K-values, 64B/row) into buffer b. Per plane: 512
  // 16B chunks; chunk ci -> row ci>>2, slot ci&3 holds global chunk
  // (ci&3)^(row&3). LDS dest linear (wave-uniform + lane*16).
  auto stage = [&](int b, int kt) {
    char* base = smem + b * 32768;
#pragma unroll
    for (int pl = 0; pl < 4; ++pl) {
      const u16* s = srcs[pl];
#pragma unroll
      for (int wq = 0; wq < 2; ++wq) {
        int ci = (w * 2 + wq) * 64 + l;
        int row = ci >> 2, cc = ci & 3;
        size_t goff = (size_t)row * 256 + kt * 32 + ((cc ^ (row & 3)) << 3);
        gl16(s + goff, base + pl * 8192 + (w * 2 + wq) * 1024 + l * 16);
      }
    }
  };

  stage(0, 0);
  __syncthreads();

  for (int kt = 0; kt < 8; ++kt) {
    int b = kt & 1;
    if (kt < 7) stage(b ^ 1, kt + 1);
    char* sAh = smem + b * 32768;
    char* sAl = sAh + 8192;
    char* sBh = sAh + 16384;
    char* sBl = sAh + 24576;
    bf16x8 ah[4], al[4];
#pragma unroll
    for (int mf = 0; mf < 4; ++mf) {
      int row = wm * 64 + mf * 16 + lr;
      int off = row * 64 + (((lh) ^ (row & 3)) << 4);
      ah[mf] = *(const bf16x8*)(sAh + off);
      al[mf] = *(const bf16x8*)(sAl + off);
    }
#pragma unroll
    for (int nf = 0; nf < 4; ++nf) {
      int row = wn * 64 + nf * 16 + lr;
      int off = row * 64 + (((lh) ^ (row & 3)) << 4);
      bf16x8 bh = *(const bf16x8*)(sBh + off);
      bf16x8 bl = *(const bf16x8*)(sBl + off);
#pragma unroll
      for (int mf = 0; mf < 4; ++mf) {
        acc[mf][nf] = __builtin_amdgcn_mfma_f32_16x16x32_bf16(ah[mf], bh, acc[mf][nf], 0, 0, 0);
        acc[mf][nf] = __builtin_amdgcn_mfma_f32_16x16x32_bf16(al[mf], bh, acc[mf][nf], 0, 0, 0);
        acc[mf][nf] = __builtin_amdgcn_mfma_f32_16x16x32_bf16(ah[mf], bl, acc[mf][nf], 0, 0, 0);
      }
    }
    __syncthreads();   // drains stage(kt+1) loads + guards buffer reuse
  }

  // ---- Q epilogue: 2 passes x 2 planes. Staged P quadrant [64][68] in LDS.
  float* sq = (float*)smem;
#pragma unroll
  for (int pass = 0; pass < 2; ++pass) {
    if (pass) __syncthreads();     // prev pass reads done before overwrite
    if (wn == pass) {
      float* buf = sq + wm * 4352;
#pragma unroll
      for (int mf = 0; mf < 4; ++mf)
#pragma unroll
        for (int nf = 0; nf < 4; ++nf)
#pragma unroll
          for (int j = 0; j < 4; ++j)
            buf[(mf * 16 + lh * 4 + j) * 68 + nf * 16 + lr] = acc[mf][nf][j];
      *(f32x4*)(buf + l * 68 + 64) = (f32x4){0.f, 0.f, 0.f, 0.f};  // pads
    }
    __syncthreads();
    int tid2 = t & 127, sel = t >> 7;
    int ax = tid2 & 63, halfj = tid2 >> 6;
    const float* S = sq + sel * 4352;
    int rr1 = ax + 1 > 63 ? 63 : ax + 1;
    int rr2 = ax + 2 > 63 ? 63 : ax + 2;
    const float* S0 = S + ax * 68;
    const float* S1 = S + rr1 * 68;
    const float* S2 = S + rr2 * 68;
    int planeIdx = (((p0 >> 6) + sel) << 6) + (q0 >> 6) + pass;
    float* Qp = P + (((size_t)planeIdx) << 12);
#pragma unroll
    for (int gi = 0; gi < 4; ++gi) {
      int g = halfj * 4 + gi;
      int c0 = g * 8;
      float r0[12], r1a[12], r2a[12];
#pragma unroll
      for (int u = 0; u < 3; ++u) {
        *(f32x4*)(r0 + u * 4) = *(const f32x4*)(S0 + c0 + u * 4);
        *(f32x4*)(r1a + u * 4) = *(const f32x4*)(S1 + c0 + u * 4);
        *(f32x4*)(r2a + u * 4) = *(const f32x4*)(S2 + c0 + u * 4);
      }
      f32x4 qv0, qv1;
#pragma unroll
      for (int e = 0; e < 4; ++e) qv0[e] = r0[e] + r1a[e + 1] + r2a[e + 2];
#pragma unroll
      for (int e = 0; e < 4; ++e) qv1[e] = r0[e + 4] + r1a[e + 5] + r2a[e + 6];
      float* Qg = Qp + g * 512 + (ax << 2);   // [g][h][ax][e]
      *(f32x4*)(Qg) = qv0;                    // h = 0
      *(f32x4*)(Qg + 256) = qv1;              // h = 1
    }
  }
}

// ---------------------------------------------------------------------------
// Kernel 4: barrier-free register-rolling diagonal reduce. Plane loads are
// 2x f32x4 from the [g][h][ax][e] layout (wave reads 2x 1KB contiguous).
// ---------------------------------------------------------------------------
__global__ __launch_bounds__(512) void reduce_kernel(char* __restrict__ slot0,
                                                     size_t slotBytes) {
  int slot = blockIdx.y;
  char* sb = slot0 + (size_t)slot * slotBytes;
  const float* QT = (const float*)(sb + SP_P);
  float* pval8 = (float*)sb;               // overlay on operand region
  u8* pidx8 = (u8*)(sb + SP_PIDX8);

  // map blockIdx.x -> (ki, segment)
  int bid = blockIdx.x;
  int ki = 0;
  for (ki = 0; ki < 123; ++ki) {
    int d = ki - 61; if (d < 0) d = -d;
    int ns = (62 - d + SEG - 1) / SEG;
    if (bid < ns) break;
    bid -= ns;
  }
  int k = ki - 61;
  int ystart = k < 0 ? -k : 0;
  int yend = k > 0 ? 61 - k : 61;
  int y0 = ystart + bid * SEG;
  int y1 = y0 + SEG; if (y1 > yend + 1) y1 = yend + 1;
  int sid0 = pre_of(ki) + (y0 - ystart);
  int pmax = yend + 2;               // last valid plane on this diagonal

  int t = threadIdx.x;
  int w = t >> 6, l = t & 63;

  float A[8], B[8], P0[8], P1[8], P2[8];

  auto ld = [&](int p, float* D) {
    const float* gp = QT + (((size_t)((p << 6) + (p + k))) << 12) + (w << 9) + (l << 2);
    *(f32x4*)(D) = *(const f32x4*)(gp);
    *(f32x4*)(D + 4) = *(const f32x4*)(gp + 256);
  };

  auto candstep = [&](int y, const float* D0, const float* D1, const float* D2) {
    float best = __uint_as_float(0xFF800000u);
    int bbb = 0;
#pragma unroll
    for (int s = 0; s < 8; ++s) {
      float c = D0[s] + D1[s] + D2[s];
      bool valid = (w * 8 + s) <= 61;
      if (valid && c > best) { best = c; bbb = s; }  // ascending s: first max
    }
    size_t o = (size_t)(sid0 + (y - y0)) * 512 + (w << 6) + l;
    pval8[o] = best;
    pidx8[o] = (u8)bbb;
  };

  ld(y0, A);
  ld(y0 + 1, B);
  ld(y0 + 2, P0);
  ld(y0 + 3 > pmax ? pmax : y0 + 3, P1);
  ld(y0 + 4 > pmax ? pmax : y0 + 4, P2);

  int y = y0;
  while (true) {
    candstep(y, A, B, P0);
#pragma unroll
    for (int s = 0; s < 8; ++s) { A[s] = B[s]; B[s] = P0[s]; }
    if (++y >= y1) break;
    ld(y + 4 > pmax ? pmax : y + 4, P0);
    candstep(y, A, B, P1);
#pragma unroll
    for (int s = 0; s < 8; ++s) { A[s] = B[s]; B[s] = P1[s]; }
    if (++y >= y1) break;
    ld(y + 4 > pmax ? pmax : y + 4, P1);
    candstep(y, A, B, P2);
#pragma unroll
    for (int s = 0; s < 8; ++s) { A[s] = B[s]; B[s] = P2[s]; }
    if (++y >= y1) break;
    ld(y + 4 > pmax ? pmax : y + 4, P2);
  }
}

// ---------------------------------------------------------------------------
// Kernel 5: combine partials over (jy, w) with exact compares; decode bb via
// one pidx8 read. Strict > with ascending (jy, w) preserves first-occurrence.
// ---------------------------------------------------------------------------
__global__ __launch_bounds__(256) void combine_kernel(const char* __restrict__ slot0,
                                                      size_t slotBytes, int b0,
                                                      float* __restrict__ resv,
                                                      int* __restrict__ residx) {
  int q = blockIdx.x * 256 + threadIdx.x;
  if (q >= NQ) return;
  int slot = blockIdx.y;
  int b = b0 + slot;
  const char* sb = slot0 + (size_t)slot * slotBytes;
  const float* pval8 = (const float*)sb;
  const u8* pidx8 = (const u8*)(sb + SP_PIDX8);
  int y = q / 62, ax = q - y * 62;
  float best = __uint_as_float(0xFF800000u);
  int bjy = 0, bw = 0;
  for (int jy = 0; jy < 62; ++jy) {
    int ki = 61 + jy - y;
    int sid = pre_of(ki) + (y < jy ? y : jy);
    const float* p = pval8 + (size_t)sid * 512 + ax;
#pragma unroll
    for (int ww = 0; ww < 8; ++ww) {
      float v = p[ww << 6];
      if (v > best) { best = v; bjy = jy; bw = ww; }
    }
  }
  int kib = 61 + bjy - y;
  int sidb = pre_of(kib) + (y < bjy ? y : bjy);
  int bb = pidx8[(size_t)sidb * 512 + (bw << 6) + ax];
  resv[(size_t)b * NQ + q] = best;
  residx[(size_t)b * NQ + q] = bjy * 62 + bw * 8 + bb;
}

// ---------------------------------------------------------------------------
// Kernel 6: assemble flow (B,64,64,2), offset (B,9,64,64,2), sim (B,1,64,64).
// ---------------------------------------------------------------------------
__global__ __launch_bounds__(256) void assemble_kernel(const float* __restrict__ res_val,
                                                       const int* __restrict__ res_idx,
                                                       float* __restrict__ out) {
  int gid = blockIdx.x * 256 + threadIdx.x;
  if (gid >= BATCH * HW) return;
  int b = gid >> 12;
  int y = (gid >> 6) & 63;
  int x = gid & 63;

  float* out_flow = out;
  float* out_off = out + (size_t)BATCH * HW * 2;
  float* out_sim = out + (size_t)BATCH * HW * 2 + (size_t)BATCH * 9 * HW * 2;

  auto flow_at = [&](int yy, int xx, float* fx, float* fy) {
    if (yy >= 0 && yy < HH && xx >= 0 && xx < WW) {
      int idx = res_idx[(size_t)b * NQ + yy * WW + xx];
      *fx = (float)(idx % WW - xx);
      *fy = (float)(idx / WW - yy);
    } else {
      *fx = 0.f;
      *fy = 0.f;
    }
  };

  float fx, fy;
  flow_at(y, x, &fx, &fy);
  size_t fo = ((size_t)b * HW + y * W + x) * 2;
  out_flow[fo + 0] = fx;
  out_flow[fo + 1] = fy;

#pragma unroll
  for (int sft = 0; sft < 9; ++sft) {
    int i = sft / 3, j = sft % 3;
    float ox, oy;
    flow_at(y - i, x - j, &ox, &oy);
    size_t o = (((size_t)b * 9 + sft) * HW + y * W + x) * 2;
    out_off[o + 0] = ox;
    out_off[o + 1] = oy;
  }

  float sim = 0.f;
  if (y >= 1 && y <= HH && x >= 1 && x <= WW) {
    float mv = res_val[(size_t)b * NQ + (y - 1) * WW + (x - 1)];
    sim = mv * (1.0f / ((3.0f + 1e-5f) * 3.0f));  // patch norms are exactly 3
  }
  out_sim[(size_t)b * HW + y * W + x] = sim;
}

// ---------------------------------------------------------------------------
extern "C" void kernel_launch(void* const* d_in, const int* in_sizes, int n_in,
                              void* d_out, int out_size, void* d_ws, size_t ws_size,
                              hipStream_t stream) {
  const float* f1 = (const float*)d_in[0];
  const float* f2 = (const float*)d_in[1];
  float* out = (float*)d_out;
  char* ws = (char*)d_ws;

  float* rnorm = (float*)(ws + OFF_RNORM);
  float* resv = (float*)(ws + OFF_RESV);
  int* residx = (int*)(ws + OFF_RESI);
  char* slot0 = ws + OFF_SLOT0;

  // adaptive image-group size from available workspace (deterministic)
  int nslots = 1;
  if (ws_size > OFF_SLOT0 + SLOT_BYTES) {
    size_t n = (ws_size - OFF_SLOT0) / SLOT_BYTES;
    nslots = n >= 8 ? 8 : (int)n;
    if (nslots < 1) nslots = 1;
  }

  norm_kernel<<<dim3(BATCH * H, 2), 256, 0, stream>>>(f1, f2, rnorm);

  for (int b0 = 0; b0 < BATCH; b0 += nslots) {
    int g = BATCH - b0 < nslots ? BATCH - b0 : nslots;
    convert_kernel<<<dim3(128, 2, g), 256, 0, stream>>>(f1, f2, rnorm, b0, slot0);
    pgemm_kernel<<<dim3(1024, g), 256, 0, stream>>>(slot0);
    reduce_kernel<<<dim3(NBLK_RED, g), 512, 0, stream>>>(slot0, SLOT_BYTES);
    combine_kernel<<<dim3(16, g), 256, 0, stream>>>(slot0, SLOT_BYTES, b0,
                                                    resv, residx);
  }

  int total = BATCH * HW;
  assemble_kernel<<<(total + 255) / 256, 256, 0, stream>>>(resv, residx, out);
}

// Round 11
// 536.821 us; speedup vs baseline: 1.1004x; 1.0073x over previous
//
#include <hip/hip_runtime.h>

typedef unsigned short u16;
typedef unsigned char u8;
typedef unsigned int u32;
typedef __bf16 bf16x8 __attribute__((ext_vector_type(8)));
typedef float f32x4 __attribute__((ext_vector_type(4)));

constexpr int BATCH = 8;
constexpr int C = 256;
constexpr int H = 64;
constexpr int W = 64;
constexpr int HW = H * W;          // 4096
constexpr int HH = 62, WW = 62;    // valid patch grid
constexpr int NQ = HH * WW;        // 3844
constexpr int SEG = 8;             // y-steps per reduce block
constexpr int NBLK_RED = 536;      // sum over diagonals of ceil(len/SEG)

// ws layout (bytes)
constexpr size_t OFF_RNORM = 0;            // 2*8*4096*4 = 262144
constexpr size_t OFF_RESV = 262144;        // 8*3844*4 = 123008 (pad 123136)
constexpr size_t OFF_RESI = 385280;
constexpr size_t OFF_SLOT0 = 508416;
// per-slot layout. pval8 (3844*512*4 = 7,872,512 B) OVERLAYS the operand
// region [0, 8MB) — operands are dead after pgemm. pidx8 after Q.
constexpr size_t SP_H1 = 0;                // 4096*256*2 = 2,097,152
constexpr size_t SP_L1 = 2097152;
constexpr size_t SP_H2 = 4194304;
constexpr size_t SP_L2 = 6291456;
constexpr size_t SP_P = 8388608;           // Q: 4096 planes * 16KB
constexpr size_t SP_PIDX8 = 75497472;      // 1,968,128 B (pad to 2MB)
constexpr size_t SLOT_BYTES = 77594624;

// async global->LDS, 16B per lane (LDS dest: wave-uniform base + lane*16)
typedef const __attribute__((address_space(1))) unsigned int* gas_ptr;
typedef __attribute__((address_space(3))) unsigned int* las_ptr;
__device__ __forceinline__ void gl16(const void* g, void* l) {
  __builtin_amdgcn_global_load_lds((gas_ptr)g, (las_ptr)l, 16, 0, 0);
}

// prefix over diagonal lengths: len(m) = 62 - |m-61|
__device__ __forceinline__ int pre_of(int ki) {
  if (ki <= 62) return ki * (ki + 1) / 2;
  int r = 123 - ki;                       // 60..1
  return 1953 + 1891 - r * (r + 1) / 2;
}

// ---------------------------------------------------------------------------
// Kernel 1: per-position reciprocal channel-L2 norm. rnorm[tensor][b][pos]
// ---------------------------------------------------------------------------
__global__ __launch_bounds__(256) void norm_kernel(const float* __restrict__ f1,
                                                   const float* __restrict__ f2,
                                                   float* __restrict__ rnorm) {
  int by = blockIdx.x;           // b*H + y
  int tensor = blockIdx.y;
  const float* f = tensor ? f2 : f1;
  int b = by >> 6, y = by & 63;
  int x = threadIdx.x & 63;
  int cq = threadIdx.x >> 6;
  const float* base = f + ((size_t)b * C) * HW + y * W + x;
  float s = 0.f;
  for (int c = cq; c < C; c += 4) {
    float v = base[(size_t)c * HW];
    s = fmaf(v, v, s);
  }
  __shared__ float sm[4][64];
  sm[cq][x] = s;
  __syncthreads();
  if (threadIdx.x < 64) {
    float t = sm[0][x] + sm[1][x] + sm[2][x] + sm[3][x];
    float nrm = fmaxf(sqrtf(t), 1e-12f);
    rnorm[((size_t)tensor * BATCH + b) * HW + y * W + x] = 1.0f / nrm;
  }
}

// ---------------------------------------------------------------------------
// Kernel 2: normalize + hi/lo bf16 split into SEPARATE u16 planes [pos][c].
// Merged over slots: grid (128 chunks, 2 tensors, g slots).
// ---------------------------------------------------------------------------
__global__ __launch_bounds__(256) void convert_kernel(const float* __restrict__ f1,
                                                      const float* __restrict__ f2,
                                                      const float* __restrict__ rnorm,
                                                      int b0, char* __restrict__ slot0) {
  int chunk = blockIdx.x;        // 0..127, 32 positions each
  int tensor = blockIdx.y;
  int sloti = blockIdx.z;
  int bi = b0 + sloti;
  char* slot = slot0 + (size_t)sloti * SLOT_BYTES;
  int pos0 = chunk * 32;
  const float* f = (tensor ? f2 : f1) + (size_t)bi * C * HW;
  const float* rn = rnorm + ((size_t)tensor * BATCH + bi) * HW + pos0;
  u16* dh = (u16*)(slot + (tensor ? SP_H2 : SP_H1)) + (size_t)pos0 * C;
  u16* dl = (u16*)(slot + (tensor ? SP_L2 : SP_L1)) + (size_t)pos0 * C;

  __shared__ u32 sm[32][257];
  int t = threadIdx.x;
  int px = t & 31, cg = t >> 5;  // cg 0..7
  float r = rn[px];
  for (int kk = 0; kk < 32; ++kk) {
    int c = (cg << 5) + kk;
    float v = f[(size_t)c * HW + pos0 + px] * r;
    __bf16 h = (__bf16)v;        // RNE
    float hf = (float)h;
    __bf16 lo = (__bf16)(v - hf);
    sm[px][c] = ((u32)__builtin_bit_cast(u16, h) << 16) | (u32)__builtin_bit_cast(u16, lo);
  }
  __syncthreads();
  int px2 = t >> 3, seg = t & 7;
  int c0 = seg * 32;
  for (int g8 = 0; g8 < 4; ++g8) {
    u32 hw0, hw1, hw2, hw3, lw0, lw1, lw2, lw3;
    u32 a, b2;
    a = sm[px2][c0 + g8 * 8 + 0]; b2 = sm[px2][c0 + g8 * 8 + 1];
    hw0 = (a >> 16) | (b2 & 0xFFFF0000u); lw0 = (a & 0xFFFFu) | (b2 << 16);
    a = sm[px2][c0 + g8 * 8 + 2]; b2 = sm[px2][c0 + g8 * 8 + 3];
    hw1 = (a >> 16) | (b2 & 0xFFFF0000u); lw1 = (a & 0xFFFFu) | (b2 << 16);
    a = sm[px2][c0 + g8 * 8 + 4]; b2 = sm[px2][c0 + g8 * 8 + 5];
    hw2 = (a >> 16) | (b2 & 0xFFFF0000u); lw2 = (a & 0xFFFFu) | (b2 << 16);
    a = sm[px2][c0 + g8 * 8 + 6]; b2 = sm[px2][c0 + g8 * 8 + 7];
    hw3 = (a >> 16) | (b2 & 0xFFFF0000u); lw3 = (a & 0xFFFFu) | (b2 << 16);
    size_t off = (size_t)px2 * C + c0 + g8 * 8;
    uint4 hv; hv.x = hw0; hv.y = hw1; hv.z = hw2; hv.w = hw3;
    uint4 lv; lv.x = lw0; lv.y = lw1; lv.z = lw2; lv.w = lw3;
    *(uint4*)(dh + off) = hv;
    *(uint4*)(dl + off) = lv;
  }
}

// ---------------------------------------------------------------------------
// Kernel 3: split-bf16 3-product MFMA GEMM + Q-epilogue.
// BK=32, double-buffered LDS (2 x 32KB), 2-phase pipeline: STAGE(buf^1,kt+1)
// issued BEFORE MFMA(buf); one __syncthreads per K-tile.
// Swizzle (parity-aware, 2-way max): LDS slot s of row r holds global
// quarter q = s ^ ((r>>1)&3). MFMA read: s = lh ^ ((row>>1)&3).
// Per quarter-wave each (row-parity, slot) pair gets exactly 2 lanes -> free.
// K accumulation order identical to R9/R10 (bit-exact canary).
// ---------------------------------------------------------------------------
__global__ __launch_bounds__(256, 2) void pgemm_kernel(char* __restrict__ slot0) {
  char* slot = slot0 + (size_t)blockIdx.y * SLOT_BYTES;
  const u16* hi1 = (const u16*)(slot + SP_H1);
  const u16* lo1 = (const u16*)(slot + SP_L1);
  const u16* hi2 = (const u16*)(slot + SP_H2);
  const u16* lo2 = (const u16*)(slot + SP_L2);
  float* P = (float*)(slot + SP_P);

  int bid = blockIdx.x;
  int swz = (bid & 7) * 128 + (bid >> 3);   // bijective XCD swizzle (1024 blocks)
  int p0 = (swz >> 5) << 7, q0 = (swz & 31) << 7;

  __shared__ __align__(16) char smem[65536];   // 2 buffers x 32KB

  int t = threadIdx.x;
  int l = t & 63, w = t >> 6, wm = w >> 1, wn = w & 1;
  int lr = l & 15, lh = l >> 4;

  const u16* srcs[4] = {hi1 + (size_t)p0 * 256, lo1 + (size_t)p0 * 256,
                        hi2 + (size_t)q0 * 256, lo2 + (size_t)q0 * 256};

  f32x4 acc[4][4];
#pragma unroll
  for (int mf = 0; mf < 4; ++mf)
#pragma unroll
    for (int nf = 0; nf < 4; ++nf)
      acc[mf][nf] = (f32x4){0.f, 0.f, 0.f, 0.f};

  // stage K-tile kt (32 K-values = 64B/row) into buffer b. Per plane: 512
  // 16B chunks; chunk ci -> row ci>>2, LDS slot s = ci&3 sources global
  // quarter q = s ^ ((row>>1)&3). LDS dest linear (wave-uniform + lane*16).
  auto stage = [&](int b, int kt) {
    char* base = smem + b * 32768;
#pragma unroll
    for (int pl = 0; pl < 4; ++pl) {
      const u16* s = srcs[pl];
#pragma unroll
      for (int wq = 0; wq < 2; ++wq) {
        int ci = (w * 2 + wq) * 64 + l;
        int row = ci >> 2, sl = ci & 3;
        int q = sl ^ ((row >> 1) & 3);
        size_t goff = (size_t)row * 256 + kt * 32 + (q << 3);
        gl16(s + goff, base + pl * 8192 + (w * 2 + wq) * 1024 + l * 16);
      }
    }
  };

  stage(0, 0);
  __syncthreads();

  for (int kt = 0; kt < 8; ++kt) {
    int b = kt & 1;
    if (kt < 7) stage(b ^ 1, kt + 1);
    char* sAh = smem + b * 32768;
    char* sAl = sAh + 8192;
    char* sBh = sAh + 16384;
    char* sBl = sAh + 24576;
    bf16x8 ah[4], al[4];
#pragma unroll
    for (int mf = 0; mf < 4; ++mf) {
      int row = wm * 64 + mf * 16 + lr;
      int off = row * 64 + ((lh ^ ((row >> 1) & 3)) << 4);
      ah[mf] = *(const bf16x8*)(sAh + off);
      al[mf] = *(const bf16x8*)(sAl + off);
    }
#pragma unroll
    for (int nf = 0; nf < 4; ++nf) {
      int row = wn * 64 + nf * 16 + lr;
      int off = row * 64 + ((lh ^ ((row >> 1) & 3)) << 4);
      bf16x8 bh = *(const bf16x8*)(sBh + off);
      bf16x8 bl = *(const bf16x8*)(sBl + off);
#pragma unroll
      for (int mf = 0; mf < 4; ++mf) {
        acc[mf][nf] = __builtin_amdgcn_mfma_f32_16x16x32_bf16(ah[mf], bh, acc[mf][nf], 0, 0, 0);
        acc[mf][nf] = __builtin_amdgcn_mfma_f32_16x16x32_bf16(al[mf], bh, acc[mf][nf], 0, 0, 0);
        acc[mf][nf] = __builtin_amdgcn_mfma_f32_16x16x32_bf16(ah[mf], bl, acc[mf][nf], 0, 0, 0);
      }
    }
    __syncthreads();   // drains stage(kt+1) loads + guards buffer reuse
  }

  // ---- Q epilogue: 2 passes x 2 planes. Staged P quadrant [64][68] in LDS.
  float* sq = (float*)smem;
#pragma unroll
  for (int pass = 0; pass < 2; ++pass) {
    if (pass) __syncthreads();     // prev pass reads done before overwrite
    if (wn == pass) {
      float* buf = sq + wm * 4352;
#pragma unroll
      for (int mf = 0; mf < 4; ++mf)
#pragma unroll
        for (int nf = 0; nf < 4; ++nf)
#pragma unroll
          for (int j = 0; j < 4; ++j)
            buf[(mf * 16 + lh * 4 + j) * 68 + nf * 16 + lr] = acc[mf][nf][j];
      *(f32x4*)(buf + l * 68 + 64) = (f32x4){0.f, 0.f, 0.f, 0.f};  // pads
    }
    __syncthreads();
    int tid2 = t & 127, sel = t >> 7;
    int ax = tid2 & 63, halfj = tid2 >> 6;
    const float* S = sq + sel * 4352;
    int rr1 = ax + 1 > 63 ? 63 : ax + 1;
    int rr2 = ax + 2 > 63 ? 63 : ax + 2;
    const float* S0 = S + ax * 68;
    const float* S1 = S + rr1 * 68;
    const float* S2 = S + rr2 * 68;
    int planeIdx = (((p0 >> 6) + sel) << 6) + (q0 >> 6) + pass;
    float* Qp = P + (((size_t)planeIdx) << 12);
#pragma unroll
    for (int gi = 0; gi < 4; ++gi) {
      int g = halfj * 4 + gi;
      int c0 = g * 8;
      float r0[12], r1a[12], r2a[12];
#pragma unroll
      for (int u = 0; u < 3; ++u) {
        *(f32x4*)(r0 + u * 4) = *(const f32x4*)(S0 + c0 + u * 4);
        *(f32x4*)(r1a + u * 4) = *(const f32x4*)(S1 + c0 + u * 4);
        *(f32x4*)(r2a + u * 4) = *(const f32x4*)(S2 + c0 + u * 4);
      }
      f32x4 qv0, qv1;
#pragma unroll
      for (int e = 0; e < 4; ++e) qv0[e] = r0[e] + r1a[e + 1] + r2a[e + 2];
#pragma unroll
      for (int e = 0; e < 4; ++e) qv1[e] = r0[e + 4] + r1a[e + 5] + r2a[e + 6];
      float* Qg = Qp + g * 512 + (ax << 2);   // [g][h][ax][e]
      *(f32x4*)(Qg) = qv0;                    // h = 0
      *(f32x4*)(Qg + 256) = qv1;              // h = 1
    }
  }
}

// ---------------------------------------------------------------------------
// Kernel 4: barrier-free register-rolling diagonal reduce. Plane loads are
// 2x f32x4 from the [g][h][ax][e] layout (wave reads 2x 1KB contiguous).
// ---------------------------------------------------------------------------
__global__ __launch_bounds__(512) void reduce_kernel(char* __restrict__ slot0,
                                                     size_t slotBytes) {
  int slot = blockIdx.y;
  char* sb = slot0 + (size_t)slot * slotBytes;
  const float* QT = (const float*)(sb + SP_P);
  float* pval8 = (float*)sb;               // overlay on operand region
  u8* pidx8 = (u8*)(sb + SP_PIDX8);

  // map blockIdx.x -> (ki, segment)
  int bid = blockIdx.x;
  int ki = 0;
  for (ki = 0; ki < 123; ++ki) {
    int d = ki - 61; if (d < 0) d = -d;
    int ns = (62 - d + SEG - 1) / SEG;
    if (bid < ns) break;
    bid -= ns;
  }
  int k = ki - 61;
  int ystart = k < 0 ? -k : 0;
  int yend = k > 0 ? 61 - k : 61;
  int y0 = ystart + bid * SEG;
  int y1 = y0 + SEG; if (y1 > yend + 1) y1 = yend + 1;
  int sid0 = pre_of(ki) + (y0 - ystart);
  int pmax = yend + 2;               // last valid plane on this diagonal

  int t = threadIdx.x;
  int w = t >> 6, l = t & 63;

  float A[8], B[8], P0[8], P1[8], P2[8];

  auto ld = [&](int p, float* D) {
    const float* gp = QT + (((size_t)((p << 6) + (p + k))) << 12) + (w << 9) + (l << 2);
    *(f32x4*)(D) = *(const f32x4*)(gp);
    *(f32x4*)(D + 4) = *(const f32x4*)(gp + 256);
  };

  auto candstep = [&](int y, const float* D0, const float* D1, const float* D2) {
    float best = __uint_as_float(0xFF800000u);
    int bbb = 0;
#pragma unroll
    for (int s = 0; s < 8; ++s) {
      float c = D0[s] + D1[s] + D2[s];
      bool valid = (w * 8 + s) <= 61;
      if (valid && c > best) { best = c; bbb = s; }  // ascending s: first max
    }
    size_t o = (size_t)(sid0 + (y - y0)) * 512 + (w << 6) + l;
    pval8[o] = best;
    pidx8[o] = (u8)bbb;
  };

  ld(y0, A);
  ld(y0 + 1, B);
  ld(y0 + 2, P0);
  ld(y0 + 3 > pmax ? pmax : y0 + 3, P1);
  ld(y0 + 4 > pmax ? pmax : y0 + 4, P2);

  int y = y0;
  while (true) {
    candstep(y, A, B, P0);
#pragma unroll
    for (int s = 0; s < 8; ++s) { A[s] = B[s]; B[s] = P0[s]; }
    if (++y >= y1) break;
    ld(y + 4 > pmax ? pmax : y + 4, P0);
    candstep(y, A, B, P1);
#pragma unroll
    for (int s = 0; s < 8; ++s) { A[s] = B[s]; B[s] = P1[s]; }
    if (++y >= y1) break;
    ld(y + 4 > pmax ? pmax : y + 4, P1);
    candstep(y, A, B, P2);
#pragma unroll
    for (int s = 0; s < 8; ++s) { A[s] = B[s]; B[s] = P2[s]; }
    if (++y >= y1) break;
    ld(y + 4 > pmax ? pmax : y + 4, P2);
  }
}

// ---------------------------------------------------------------------------
// Kernel 5: combine partials over (jy, w) with exact compares; decode bb via
// one pidx8 read. Strict > with ascending (jy, w) preserves first-occurrence.
// ---------------------------------------------------------------------------
__global__ __launch_bounds__(256) void combine_kernel(const char* __restrict__ slot0,
                                                      size_t slotBytes, int b0,
                                                      float* __restrict__ resv,
                                                      int* __restrict__ residx) {
  int q = blockIdx.x * 256 + threadIdx.x;
  if (q >= NQ) return;
  int slot = blockIdx.y;
  int b = b0 + slot;
  const char* sb = slot0 + (size_t)slot * slotBytes;
  const float* pval8 = (const float*)sb;
  const u8* pidx8 = (const u8*)(sb + SP_PIDX8);
  int y = q / 62, ax = q - y * 62;
  float best = __uint_as_float(0xFF800000u);
  int bjy = 0, bw = 0;
  for (int jy = 0; jy < 62; ++jy) {
    int ki = 61 + jy - y;
    int sid = pre_of(ki) + (y < jy ? y : jy);
    const float* p = pval8 + (size_t)sid * 512 + ax;
#pragma unroll
    for (int ww = 0; ww < 8; ++ww) {
      float v = p[ww << 6];
      if (v > best) { best = v; bjy = jy; bw = ww; }
    }
  }
  int kib = 61 + bjy - y;
  int sidb = pre_of(kib) + (y < bjy ? y : bjy);
  int bb = pidx8[(size_t)sidb * 512 + (bw << 6) + ax];
  resv[(size_t)b * NQ + q] = best;
  residx[(size_t)b * NQ + q] = bjy * 62 + bw * 8 + bb;
}

// ---------------------------------------------------------------------------
// Kernel 6: assemble flow (B,64,64,2), offset (B,9,64,64,2), sim (B,1,64,64).
// ---------------------------------------------------------------------------
__global__ __launch_bounds__(256) void assemble_kernel(const float* __restrict__ res_val,
                                                       const int* __restrict__ res_idx,
                                                       float* __restrict__ out) {
  int gid = blockIdx.x * 256 + threadIdx.x;
  if (gid >= BATCH * HW) return;
  int b = gid >> 12;
  int y = (gid >> 6) & 63;
  int x = gid & 63;

  float* out_flow = out;
  float* out_off = out + (size_t)BATCH * HW * 2;
  float* out_sim = out + (size_t)BATCH * HW * 2 + (size_t)BATCH * 9 * HW * 2;

  auto flow_at = [&](int yy, int xx, float* fx, float* fy) {
    if (yy >= 0 && yy < HH && xx >= 0 && xx < WW) {
      int idx = res_idx[(size_t)b * NQ + yy * WW + xx];
      *fx = (float)(idx % WW - xx);
      *fy = (float)(idx / WW - yy);
    } else {
      *fx = 0.f;
      *fy = 0.f;
    }
  };

  float fx, fy;
  flow_at(y, x, &fx, &fy);
  size_t fo = ((size_t)b * HW + y * W + x) * 2;
  out_flow[fo + 0] = fx;
  out_flow[fo + 1] = fy;

#pragma unroll
  for (int sft = 0; sft < 9; ++sft) {
    int i = sft / 3, j = sft % 3;
    float ox, oy;
    flow_at(y - i, x - j, &ox, &oy);
    size_t o = (((size_t)b * 9 + sft) * HW + y * W + x) * 2;
    out_off[o + 0] = ox;
    out_off[o + 1] = oy;
  }

  float sim = 0.f;
  if (y >= 1 && y <= HH && x >= 1 && x <= WW) {
    float mv = res_val[(size_t)b * NQ + (y - 1) * WW + (x - 1)];
    sim = mv * (1.0f / ((3.0f + 1e-5f) * 3.0f));  // patch norms are exactly 3
  }
  out_sim[(size_t)b * HW + y * W + x] = sim;
}

// ---------------------------------------------------------------------------
extern "C" void kernel_launch(void* const* d_in, const int* in_sizes, int n_in,
                              void* d_out, int out_size, void* d_ws, size_t ws_size,
                              hipStream_t stream) {
  const float* f1 = (const float*)d_in[0];
  const float* f2 = (const float*)d_in[1];
  float* out = (float*)d_out;
  char* ws = (char*)d_ws;

  float* rnorm = (float*)(ws + OFF_RNORM);
  float* resv = (float*)(ws + OFF_RESV);
  int* residx = (int*)(ws + OFF_RESI);
  char* slot0 = ws + OFF_SLOT0;

  // adaptive image-group size from available workspace (deterministic)
  int nslots = 1;
  if (ws_size > OFF_SLOT0 + SLOT_BYTES) {
    size_t n = (ws_size - OFF_SLOT0) / SLOT_BYTES;
    nslots = n >= 8 ? 8 : (int)n;
    if (nslots < 1) nslots = 1;
  }

  norm_kernel<<<dim3(BATCH * H, 2), 256, 0, stream>>>(f1, f2, rnorm);

  for (int b0 = 0; b0 < BATCH; b0 += nslots) {
    int g = BATCH - b0 < nslots ? BATCH - b0 : nslots;
    convert_kernel<<<dim3(128, 2, g), 256, 0, stream>>>(f1, f2, rnorm, b0, slot0);
    pgemm_kernel<<<dim3(1024, g), 256, 0, stream>>>(slot0);
    reduce_kernel<<<dim3(NBLK_RED, g), 512, 0, stream>>>(slot0, SLOT_BYTES);
    combine_kernel<<<dim3(16, g), 256, 0, stream>>>(slot0, SLOT_BYTES, b0,
                                                    resv, residx);
  }

  int total = BATCH * HW;
  assemble_kernel<<<(total + 255) / 256, 256, 0, stream>>>(resv, residx, out);
}